// Round 4
// baseline (635.646 us; speedup 1.0000x reference)
//
#include <hip/hip_runtime.h>

// VoxelPooler via bucket sort.
// R5: bucket sort, 622us. R6: 4-pt float4 gather (256-B rows), 600us.
// R7: channel-sliced gather (64-B slices)+NT: 716us — 4x gather transaction
//     count dominated. R8: merged-yt (800-B segs, 3 blk/CU)+NT: 626us.
// Cross-round ablation: R7->R8 (-90us, read granule) and R8->R6 (-26us,
// occupancy; write granule anti-correlated) => gather is LATENCY-bound,
// write pattern second-order. R9 = R6 structure exactly (TILE_Y=100,
// 12800 buckets, 26KB LDS, 6 blk/CU, plain stores) + 4-deep gather ILP:
// each lane owns 4 consecutive points, issues 4 independent float4 loads
// before consuming (vmcnt depth 4 vs 1).
// geometry [B=4, N=6, D=41, H=16, W=44, 3] f32
// features [B, N, D, H, W, C=64] f32
// out      [B, Z*C=512, X=200, Y=200] f32

#define GRID_X 200
#define GRID_Y 200
#define GRID_Z 8
#define NCH 64
#define NB 4
#define PTS_PER_BATCH (6 * 41 * 16 * 44)   // 173184
#define TOTAL_POINTS (NB * PTS_PER_BATCH)  // 692736
#define OUT_FLOATS ((long long)NB * GRID_Z * NCH * GRID_X * GRID_Y)  // 81,920,000

#define YT 2             // y tiles per x-row
#define TILE_Y 100       // GRID_Y / YT
#define NBUCKET (NB * GRID_Z * GRID_X * YT)   // 12800
#define LDS_STRIDE 65    // acc[y][c] padded: gather 2-way banks, epilogue ok

// ws layout (ints):
// cnt[NBUCKET] | starts[NBUCKET+1] | cursor[NBUCKET] | sorted[TOTAL_POINTS] | pcode[TOTAL_POINTS]
#define WS_CNT     0
#define WS_STARTS  (NBUCKET)
#define WS_CURSOR  (2 * NBUCKET + 1)
#define WS_SORTED  (3 * NBUCKET + 1)
#define WS_PCODE   (3 * NBUCKET + 1 + TOTAL_POINTS)
#define WS_INTS    (3 * NBUCKET + 1 + 2 * TOTAL_POINTS)

__device__ __forceinline__ bool point_voxel(const float* __restrict__ geom,
                                            const float* __restrict__ vsz,
                                            const float* __restrict__ vorg,
                                            int i, int& vx, int& vy, int& vz) {
    float px = geom[(size_t)i * 3 + 0];
    float py = geom[(size_t)i * 3 + 1];
    float pz = geom[(size_t)i * 3 + 2];
    // Exact IEEE divide + floorf to match the numpy reference at bin edges.
    vx = (int)floorf((px - vorg[0]) / vsz[0]);
    vy = (int)floorf((py - vorg[1]) / vsz[1]);
    vz = (int)floorf((pz - vorg[2]) / vsz[2]);
    return (vx >= 0 && vx < GRID_X && vy >= 0 && vy < GRID_Y &&
            vz >= 0 && vz < GRID_Z);
}

__global__ __launch_bounds__(256) void zero_cnt_kernel(int* __restrict__ cnt) {
    int i = blockIdx.x * 256 + threadIdx.x;
    if (i < NBUCKET) cnt[i] = 0;
}

// Histogram + cache packed (bucket, y_local) per point so scatter_idx skips
// the geometry re-read. pcode: bit31=valid, bits[20:14]=yl, bits[13:0]=bucket.
__global__ __launch_bounds__(256) void hist_kernel(
    const float* __restrict__ geom, const float* __restrict__ vsz,
    const float* __restrict__ vorg, int* __restrict__ cnt,
    unsigned* __restrict__ pcode) {
    int i = blockIdx.x * 256 + threadIdx.x;
    if (i >= TOTAL_POINTS) return;
    int vx, vy, vz;
    unsigned code = 0;
    if (point_voxel(geom, vsz, vorg, i, vx, vy, vz)) {
        int b = i / PTS_PER_BATCH;
        int yt = vy / TILE_Y;
        int yl = vy - yt * TILE_Y;
        int bucket = ((b * GRID_Z + vz) * GRID_X + vx) * YT + yt;
        code = 0x80000000u | ((unsigned)yl << 14) | (unsigned)bucket;
        atomicAdd(&cnt[bucket], 1);
    }
    pcode[i] = code;
}

// One block, 256 threads, each owns 50 contiguous counters.
__global__ __launch_bounds__(256) void scan_kernel(
    const int* __restrict__ cnt, int* __restrict__ starts, int* __restrict__ cursor) {
    __shared__ int partial[256];
    int t = threadIdx.x;
    const int CHUNK = NBUCKET / 256;   // 50
    int base = t * CHUNK;
    int s = 0;
    for (int j = 0; j < CHUNK; ++j) s += cnt[base + j];
    partial[t] = s;
    __syncthreads();
    for (int off = 1; off < 256; off <<= 1) {
        int v = (t >= off) ? partial[t - off] : 0;
        __syncthreads();
        partial[t] += v;
        __syncthreads();
    }
    int run = partial[t] - s;   // exclusive prefix of this chunk
    for (int j = 0; j < CHUNK; ++j) {
        int c = cnt[base + j];
        starts[base + j] = run;
        cursor[base + j] = run;
        run += c;
    }
    if (t == 255) starts[NBUCKET] = run;
}

__global__ __launch_bounds__(256) void scatter_idx_kernel(
    const unsigned* __restrict__ pcode, int* __restrict__ cursor,
    unsigned* __restrict__ sorted) {
    int i = blockIdx.x * 256 + threadIdx.x;
    if (i >= TOTAL_POINTS) return;
    unsigned code = pcode[i];
    if (!(code & 0x80000000u)) return;
    int bucket = (int)(code & 0x3FFFu);
    unsigned yl = (code >> 14) & 0x7Fu;
    int pos = atomicAdd(&cursor[bucket], 1);
    sorted[pos] = (unsigned)i | (yl << 20);   // i < 2^20, yl < 128
}

// One block per bucket (b, z, x, yt). Gather: 16 points per wave-iteration;
// each lane owns 4 CONSECUTIVE points and issues 4 independent float4 loads
// before consuming any (deep vmcnt queue -> latency-bound gather becomes
// BW-bound). Accumulate acc[y][c] in LDS, dense float4 write-out.
__global__ __launch_bounds__(256) void pool_kernel(
    const float4* __restrict__ feat4, const unsigned* __restrict__ sorted,
    const int* __restrict__ starts, float4* __restrict__ out4) {
    __shared__ __align__(16) float acc[TILE_Y * LDS_STRIDE];   // 26000 B
    int t = threadIdx.x;
    int bid = blockIdx.x;

    // zero LDS with float4 stores: 6500 floats = 1625 float4
    float4* a4 = (float4*)acc;
    for (int i = t; i < TILE_Y * LDS_STRIDE / 4; i += 256)
        a4[i] = make_float4(0.f, 0.f, 0.f, 0.f);
    __syncthreads();

    int s0 = starts[bid];
    int s1 = starts[bid + 1];
    int w = t >> 6;            // wave 0..3
    int g = (t >> 4) & 3;      // point-quad slot within wave
    int l = t & 15;            // float4 slot: channels 4l..4l+3

    for (int p0 = s0 + w * 16; p0 < s1; p0 += 64) {
        int pA = p0 + 4 * g;
        int n = s1 - pA;       // valid points in this lane's quad (may be <=0)
        unsigned pk0 = 0, pk1 = 0, pk2 = 0, pk3 = 0;
        float4 f0, f1, f2, f3;
        // issue all index reads, then all feature loads (independent),
        // THEN consume: compiler emits 4 back-to-back global_load_dwordx4
        // with a single waitcnt ladder.
        if (n > 0) pk0 = sorted[pA + 0];
        if (n > 1) pk1 = sorted[pA + 1];
        if (n > 2) pk2 = sorted[pA + 2];
        if (n > 3) pk3 = sorted[pA + 3];
        if (n > 0) f0 = feat4[(size_t)(pk0 & 0xFFFFFu) * 16 + l];
        if (n > 1) f1 = feat4[(size_t)(pk1 & 0xFFFFFu) * 16 + l];
        if (n > 2) f2 = feat4[(size_t)(pk2 & 0xFFFFFu) * 16 + l];
        if (n > 3) f3 = feat4[(size_t)(pk3 & 0xFFFFFu) * 16 + l];
        if (n > 0) {
            float* r = &acc[(pk0 >> 20) * LDS_STRIDE + 4 * l];
            atomicAdd(r + 0, f0.x); atomicAdd(r + 1, f0.y);
            atomicAdd(r + 2, f0.z); atomicAdd(r + 3, f0.w);
        }
        if (n > 1) {
            float* r = &acc[(pk1 >> 20) * LDS_STRIDE + 4 * l];
            atomicAdd(r + 0, f1.x); atomicAdd(r + 1, f1.y);
            atomicAdd(r + 2, f1.z); atomicAdd(r + 3, f1.w);
        }
        if (n > 2) {
            float* r = &acc[(pk2 >> 20) * LDS_STRIDE + 4 * l];
            atomicAdd(r + 0, f2.x); atomicAdd(r + 1, f2.y);
            atomicAdd(r + 2, f2.z); atomicAdd(r + 3, f2.w);
        }
        if (n > 3) {
            float* r = &acc[(pk3 >> 20) * LDS_STRIDE + 4 * l];
            atomicAdd(r + 0, f3.x); atomicAdd(r + 1, f3.y);
            atomicAdd(r + 2, f3.z); atomicAdd(r + 3, f3.w);
        }
    }
    __syncthreads();

    // bid = ((b*GZ+z)*GX + x)*YT + yt
    int yt = bid & 1;
    int x = (bid >> 1) % GRID_X;
    int bz = (bid >> 1) / GRID_X;   // b*GRID_Z + z

    // 64 channels x 25 float4 (=100 y) = 1600 float4 stores, coalesced.
    for (int i = t; i < NCH * (TILE_Y / 4); i += 256) {
        int cc = i / (TILE_Y / 4);
        int j = i % (TILE_Y / 4);
        int y0 = 4 * j;
        float4 v = make_float4(acc[(y0 + 0) * LDS_STRIDE + cc],
                               acc[(y0 + 1) * LDS_STRIDE + cc],
                               acc[(y0 + 2) * LDS_STRIDE + cc],
                               acc[(y0 + 3) * LDS_STRIDE + cc]);
        // float index: (((bz*64+cc)*200 + x)*200 + yt*100 + 4j), /4 below
        size_t o4 = (((size_t)bz * NCH + cc) * GRID_X + x) * (GRID_Y / 4)
                    + yt * (TILE_Y / 4) + j;
        out4[o4] = v;
    }
}

// ---------- fallback path (R4): atomic scatter ----------
__global__ __launch_bounds__(256) void zero_out_kernel(float4* __restrict__ out) {
    const long long n4 = OUT_FLOATS / 4;
    long long stride = (long long)gridDim.x * blockDim.x;
    for (long long i = blockIdx.x * (long long)blockDim.x + threadIdx.x;
         i < n4; i += stride)
        out[i] = make_float4(0.f, 0.f, 0.f, 0.f);
}

__global__ __launch_bounds__(256) void voxel_scatter_kernel(
    const float* __restrict__ geom, const float* __restrict__ feat,
    const float* __restrict__ vsz, const float* __restrict__ vorg,
    float* __restrict__ out) {
    int gid = blockIdx.x * blockDim.x + threadIdx.x;
    int pt = gid >> 6;
    int c = gid & 63;
    if (pt >= TOTAL_POINTS) return;
    int vx, vy, vz;
    if (!point_voxel(geom, vsz, vorg, pt, vx, vy, vz)) return;
    int b = pt / PTS_PER_BATCH;
    float f = feat[(size_t)pt * NCH + c];
    size_t idx = ((((size_t)b * GRID_Z + vz) * NCH + c) * GRID_X + vx) * GRID_Y + vy;
    atomicAdd(out + idx, f);
}

extern "C" void kernel_launch(void* const* d_in, const int* in_sizes, int n_in,
                              void* d_out, int out_size, void* d_ws, size_t ws_size,
                              hipStream_t stream) {
    const float* geom = (const float*)d_in[0];
    const float* feat = (const float*)d_in[1];
    const float* vsz  = (const float*)d_in[2];
    const float* vorg = (const float*)d_in[3];
    float* out = (float*)d_out;

    if (ws_size >= (size_t)WS_INTS * sizeof(int)) {
        int* ws = (int*)d_ws;
        int* cnt = ws + WS_CNT;
        int* starts = ws + WS_STARTS;
        int* cursor = ws + WS_CURSOR;
        unsigned* sorted = (unsigned*)(ws + WS_SORTED);
        unsigned* pcode  = (unsigned*)(ws + WS_PCODE);

        zero_cnt_kernel<<<(NBUCKET + 255) / 256, 256, 0, stream>>>(cnt);
        hist_kernel<<<TOTAL_POINTS / 256, 256, 0, stream>>>(geom, vsz, vorg, cnt, pcode);
        scan_kernel<<<1, 256, 0, stream>>>(cnt, starts, cursor);
        scatter_idx_kernel<<<TOTAL_POINTS / 256, 256, 0, stream>>>(pcode, cursor, sorted);
        pool_kernel<<<NBUCKET, 256, 0, stream>>>(
            (const float4*)feat, sorted, starts, (float4*)out);
    } else {
        // ws too small: R4 atomic-scatter fallback
        zero_out_kernel<<<2048, 256, 0, stream>>>((float4*)out);
        const long long total_threads = (long long)TOTAL_POINTS * NCH;
        voxel_scatter_kernel<<<(int)((total_threads + 255) / 256), 256, 0, stream>>>(
            geom, feat, vsz, vorg, out);
    }
}

// Round 5
// 597.738 us; speedup vs baseline: 1.0634x; 1.0634x over previous
//
#include <hip/hip_runtime.h>

// VoxelPooler via bucket sort.
// R5: bucket sort 622us. R6: 4-pt float4 gather (256-B rows), 600us.
// R7: channel-sliced gather + NT: 716us (4x read transactions dominated).
// R8: merged-yt + NT: 626us. R9: 4-deep gather ILP: 635us, pool=225us —
//     ILP guards/divergence cost more than queue depth bought. REVERTED.
// R9 counters (first direct pool measurement): pool 225us, 1.78 TB/s,
// WRITE=333MB (dense out), FETCH=59MB (features are L3-resident!),
// VALUBusy 6.7%, bank-conflicts 4% of cycles. Nothing busy => the write
// stream is DRAM-page-thrashing: consecutive bids (adjacent x = adjacent
// addresses) round-robin across 8 XCDs, so each L2 evicts sparse 400-B
// fragments. R10 = R6 structure + bijective XCD-chunked bid swizzle:
// each XCD owns 1600 consecutive buckets; its ~32 concurrent blocks give
// per-channel contiguous ~12.8KB write windows -> page-local evictions.
// geometry [B=4, N=6, D=41, H=16, W=44, 3] f32
// features [B, N, D, H, W, C=64] f32
// out      [B, Z*C=512, X=200, Y=200] f32

#define GRID_X 200
#define GRID_Y 200
#define GRID_Z 8
#define NCH 64
#define NB 4
#define PTS_PER_BATCH (6 * 41 * 16 * 44)   // 173184
#define TOTAL_POINTS (NB * PTS_PER_BATCH)  // 692736
#define OUT_FLOATS ((long long)NB * GRID_Z * NCH * GRID_X * GRID_Y)  // 81,920,000

#define YT 2             // y tiles per x-row
#define TILE_Y 100       // GRID_Y / YT
#define NBUCKET (NB * GRID_Z * GRID_X * YT)   // 12800
#define NXCD 8
#define LDS_STRIDE 65    // acc[y][c] padded: gather 2-way banks, epilogue ok

// ws layout (ints):
// cnt[NBUCKET] | starts[NBUCKET+1] | cursor[NBUCKET] | sorted[TOTAL_POINTS] | pcode[TOTAL_POINTS]
#define WS_CNT     0
#define WS_STARTS  (NBUCKET)
#define WS_CURSOR  (2 * NBUCKET + 1)
#define WS_SORTED  (3 * NBUCKET + 1)
#define WS_PCODE   (3 * NBUCKET + 1 + TOTAL_POINTS)
#define WS_INTS    (3 * NBUCKET + 1 + 2 * TOTAL_POINTS)

__device__ __forceinline__ bool point_voxel(const float* __restrict__ geom,
                                            const float* __restrict__ vsz,
                                            const float* __restrict__ vorg,
                                            int i, int& vx, int& vy, int& vz) {
    float px = geom[(size_t)i * 3 + 0];
    float py = geom[(size_t)i * 3 + 1];
    float pz = geom[(size_t)i * 3 + 2];
    // Exact IEEE divide + floorf to match the numpy reference at bin edges.
    vx = (int)floorf((px - vorg[0]) / vsz[0]);
    vy = (int)floorf((py - vorg[1]) / vsz[1]);
    vz = (int)floorf((pz - vorg[2]) / vsz[2]);
    return (vx >= 0 && vx < GRID_X && vy >= 0 && vy < GRID_Y &&
            vz >= 0 && vz < GRID_Z);
}

__global__ __launch_bounds__(256) void zero_cnt_kernel(int* __restrict__ cnt) {
    int i = blockIdx.x * 256 + threadIdx.x;
    if (i < NBUCKET) cnt[i] = 0;
}

// Histogram + cache packed (bucket, y_local) per point so scatter_idx skips
// the geometry re-read. pcode: bit31=valid, bits[20:14]=yl, bits[13:0]=bucket.
__global__ __launch_bounds__(256) void hist_kernel(
    const float* __restrict__ geom, const float* __restrict__ vsz,
    const float* __restrict__ vorg, int* __restrict__ cnt,
    unsigned* __restrict__ pcode) {
    int i = blockIdx.x * 256 + threadIdx.x;
    if (i >= TOTAL_POINTS) return;
    int vx, vy, vz;
    unsigned code = 0;
    if (point_voxel(geom, vsz, vorg, i, vx, vy, vz)) {
        int b = i / PTS_PER_BATCH;
        int yt = vy / TILE_Y;
        int yl = vy - yt * TILE_Y;
        int bucket = ((b * GRID_Z + vz) * GRID_X + vx) * YT + yt;
        code = 0x80000000u | ((unsigned)yl << 14) | (unsigned)bucket;
        atomicAdd(&cnt[bucket], 1);
    }
    pcode[i] = code;
}

// One block, 256 threads, each owns 50 contiguous counters.
__global__ __launch_bounds__(256) void scan_kernel(
    const int* __restrict__ cnt, int* __restrict__ starts, int* __restrict__ cursor) {
    __shared__ int partial[256];
    int t = threadIdx.x;
    const int CHUNK = NBUCKET / 256;   // 50
    int base = t * CHUNK;
    int s = 0;
    for (int j = 0; j < CHUNK; ++j) s += cnt[base + j];
    partial[t] = s;
    __syncthreads();
    for (int off = 1; off < 256; off <<= 1) {
        int v = (t >= off) ? partial[t - off] : 0;
        __syncthreads();
        partial[t] += v;
        __syncthreads();
    }
    int run = partial[t] - s;   // exclusive prefix of this chunk
    for (int j = 0; j < CHUNK; ++j) {
        int c = cnt[base + j];
        starts[base + j] = run;
        cursor[base + j] = run;
        run += c;
    }
    if (t == 255) starts[NBUCKET] = run;
}

__global__ __launch_bounds__(256) void scatter_idx_kernel(
    const unsigned* __restrict__ pcode, int* __restrict__ cursor,
    unsigned* __restrict__ sorted) {
    int i = blockIdx.x * 256 + threadIdx.x;
    if (i >= TOTAL_POINTS) return;
    unsigned code = pcode[i];
    if (!(code & 0x80000000u)) return;
    int bucket = (int)(code & 0x3FFFu);
    unsigned yl = (code >> 14) & 0x7Fu;
    int pos = atomicAdd(&cursor[bucket], 1);
    sorted[pos] = (unsigned)i | (yl << 20);   // i < 2^20, yl < 128
}

// One block per bucket (b, z, x, yt). Gather: 4 points per wave-iteration,
// 16 lanes x float4 each (1 KB / wave load instr). Accumulate acc[y][c]
// in LDS, dense float4 write-out. XCD-chunked bid swizzle: each XCD owns
// 1600 CONSECUTIVE buckets so concurrent blocks on one XCD write adjacent
// addresses -> L2 aggregates full-page evictions (the R9 1.8 TB/s fix).
__global__ __launch_bounds__(256) void pool_kernel(
    const float4* __restrict__ feat4, const unsigned* __restrict__ sorted,
    const int* __restrict__ starts, float4* __restrict__ out4) {
    __shared__ __align__(16) float acc[TILE_Y * LDS_STRIDE];   // 26000 B
    int t = threadIdx.x;
    // bijective chunked swizzle (NBUCKET % NXCD == 0): physical round-robin
    // dispatch -> each XCD processes a contiguous bucket chunk.
    int bid = (blockIdx.x % NXCD) * (NBUCKET / NXCD) + blockIdx.x / NXCD;

    // zero LDS with float4 stores: 6500 floats = 1625 float4
    float4* a4 = (float4*)acc;
    for (int i = t; i < TILE_Y * LDS_STRIDE / 4; i += 256)
        a4[i] = make_float4(0.f, 0.f, 0.f, 0.f);
    __syncthreads();

    int s0 = starts[bid];
    int s1 = starts[bid + 1];
    int w = t >> 6;            // wave 0..3
    int g = (t >> 4) & 3;      // point slot within wave
    int l = t & 15;            // float4 slot: channels 4l..4l+3

    for (int p0 = s0 + w * 4; p0 < s1; p0 += 16) {
        int p = p0 + g;
        if (p < s1) {
            unsigned pk = sorted[p];
            unsigned idx = pk & 0xFFFFFu;
            unsigned yl = pk >> 20;
            float4 f = feat4[(size_t)idx * 16 + l];
            float* row = &acc[yl * LDS_STRIDE + 4 * l];
            atomicAdd(row + 0, f.x);
            atomicAdd(row + 1, f.y);
            atomicAdd(row + 2, f.z);
            atomicAdd(row + 3, f.w);
        }
    }
    __syncthreads();

    // bid = ((b*GZ+z)*GX + x)*YT + yt
    int yt = bid & 1;
    int x = (bid >> 1) % GRID_X;
    int bz = (bid >> 1) / GRID_X;   // b*GRID_Z + z

    // 64 channels x 25 float4 (=100 y) = 1600 float4 stores, coalesced.
    for (int i = t; i < NCH * (TILE_Y / 4); i += 256) {
        int cc = i / (TILE_Y / 4);
        int j = i % (TILE_Y / 4);
        int y0 = 4 * j;
        float4 v = make_float4(acc[(y0 + 0) * LDS_STRIDE + cc],
                               acc[(y0 + 1) * LDS_STRIDE + cc],
                               acc[(y0 + 2) * LDS_STRIDE + cc],
                               acc[(y0 + 3) * LDS_STRIDE + cc]);
        // float index: (((bz*64+cc)*200 + x)*200 + yt*100 + 4j), /4 below
        size_t o4 = (((size_t)bz * NCH + cc) * GRID_X + x) * (GRID_Y / 4)
                    + yt * (TILE_Y / 4) + j;
        out4[o4] = v;
    }
}

// ---------- fallback path (R4): atomic scatter ----------
__global__ __launch_bounds__(256) void zero_out_kernel(float4* __restrict__ out) {
    const long long n4 = OUT_FLOATS / 4;
    long long stride = (long long)gridDim.x * blockDim.x;
    for (long long i = blockIdx.x * (long long)blockDim.x + threadIdx.x;
         i < n4; i += stride)
        out[i] = make_float4(0.f, 0.f, 0.f, 0.f);
}

__global__ __launch_bounds__(256) void voxel_scatter_kernel(
    const float* __restrict__ geom, const float* __restrict__ feat,
    const float* __restrict__ vsz, const float* __restrict__ vorg,
    float* __restrict__ out) {
    int gid = blockIdx.x * blockDim.x + threadIdx.x;
    int pt = gid >> 6;
    int c = gid & 63;
    if (pt >= TOTAL_POINTS) return;
    int vx, vy, vz;
    if (!point_voxel(geom, vsz, vorg, pt, vx, vy, vz)) return;
    int b = pt / PTS_PER_BATCH;
    float f = feat[(size_t)pt * NCH + c];
    size_t idx = ((((size_t)b * GRID_Z + vz) * NCH + c) * GRID_X + vx) * GRID_Y + vy;
    atomicAdd(out + idx, f);
}

extern "C" void kernel_launch(void* const* d_in, const int* in_sizes, int n_in,
                              void* d_out, int out_size, void* d_ws, size_t ws_size,
                              hipStream_t stream) {
    const float* geom = (const float*)d_in[0];
    const float* feat = (const float*)d_in[1];
    const float* vsz  = (const float*)d_in[2];
    const float* vorg = (const float*)d_in[3];
    float* out = (float*)d_out;

    if (ws_size >= (size_t)WS_INTS * sizeof(int)) {
        int* ws = (int*)d_ws;
        int* cnt = ws + WS_CNT;
        int* starts = ws + WS_STARTS;
        int* cursor = ws + WS_CURSOR;
        unsigned* sorted = (unsigned*)(ws + WS_SORTED);
        unsigned* pcode  = (unsigned*)(ws + WS_PCODE);

        zero_cnt_kernel<<<(NBUCKET + 255) / 256, 256, 0, stream>>>(cnt);
        hist_kernel<<<TOTAL_POINTS / 256, 256, 0, stream>>>(geom, vsz, vorg, cnt, pcode);
        scan_kernel<<<1, 256, 0, stream>>>(cnt, starts, cursor);
        scatter_idx_kernel<<<TOTAL_POINTS / 256, 256, 0, stream>>>(pcode, cursor, sorted);
        pool_kernel<<<NBUCKET, 256, 0, stream>>>(
            (const float4*)feat, sorted, starts, (float4*)out);
    } else {
        // ws too small: R4 atomic-scatter fallback
        zero_out_kernel<<<2048, 256, 0, stream>>>((float4*)out);
        const long long total_threads = (long long)TOTAL_POINTS * NCH;
        voxel_scatter_kernel<<<(int)((total_threads + 255) / 256), 256, 0, stream>>>(
            geom, feat, vsz, vorg, out);
    }
}